// Round 5
// baseline (431.278 us; speedup 1.0000x reference)
//
#include <hip/hip_runtime.h>
#include <hip/hip_bf16.h>
#include <cstdint>

#define B_ 64
#define S_ 2048
#define D_ 512
#define H_ 512

typedef short s16x8 __attribute__((ext_vector_type(8)));
typedef float f32x4 __attribute__((ext_vector_type(4)));
typedef unsigned short u16x8 __attribute__((ext_vector_type(8)));

static __device__ __forceinline__ unsigned short f2bf(float f) {
  __bf16 h = (__bf16)f;
  return __builtin_bit_cast(unsigned short, h);
}
static __device__ __forceinline__ float bf2f(unsigned short u) {
  unsigned int w = ((unsigned int)u) << 16;
  return __builtin_bit_cast(float, w);
}

// ---------------- mask dtype detection (parallel) ----------------
__global__ void k_zero(int* __restrict__ flag) {
  if (threadIdx.x == 0) *flag = 0;
}
__global__ void k_detect(const unsigned int* __restrict__ mw, int* __restrict__ flag) {
  int i = blockIdx.x * 256 + threadIdx.x;  // 128 blocks x 256 = 32768
  unsigned w = mw[i];
  int bits = 0;
  if (w == 0x3F800000u) bits = 2;
  else if (w > 1u) bits = 1;
  unsigned long long a1 = __ballot(bits & 1);
  unsigned long long a2 = __ballot(bits & 2);
  if ((threadIdx.x & 63) == 0) {
    int v = (a1 ? 1 : 0) | (a2 ? 2 : 0);
    if (v) atomicOr(flag, v);
  }
}

// ---------------- W_ctx f32 -> bf16 ----------------
__global__ void k_cvt(const float* __restrict__ W, unsigned short* __restrict__ Wb) {
  int i = (blockIdx.x * 256 + threadIdx.x) * 8;
  float4 a = *(const float4*)(W + i);
  float4 c = *(const float4*)(W + i + 4);
  ushort4 o0 = make_ushort4(f2bf(a.x), f2bf(a.y), f2bf(a.z), f2bf(a.w));
  ushort4 o1 = make_ushort4(f2bf(c.x), f2bf(c.y), f2bf(c.z), f2bf(c.w));
  *(ushort4*)(Wb + i) = o0;
  *(ushort4*)(Wb + i + 4) = o1;
}

// ---------------- context f32 -> bf16 (full tensor, streaming) ----------------
__global__ __launch_bounds__(256) void k_cvtctx(const float* __restrict__ in,
                                                unsigned short* __restrict__ out) {
  const int t = blockIdx.x * 256 + threadIdx.x;  // 2048*256 = 524288 threads
#pragma unroll
  for (int i = 0; i < 16; ++i) {
    size_t e = ((size_t)i * 524288 + t) * 8;
    float4 a = *(const float4*)(in + e);
    float4 c = *(const float4*)(in + e + 4);
    u16x8 o;
    o[0] = f2bf(a.x); o[1] = f2bf(a.y); o[2] = f2bf(a.z); o[3] = f2bf(a.w);
    o[4] = f2bf(c.x); o[5] = f2bf(c.y); o[6] = f2bf(c.z); o[7] = f2bf(c.w);
    *(u16x8*)(out + e) = o;
  }
}

// ---------------- inp' = x @ W_in^T + b_in + b_ctx ----------------
__global__ void k_inp(const float* __restrict__ x, const float* __restrict__ W_in,
                      const float* __restrict__ b_in, const float* __restrict__ b_ctx,
                      float* __restrict__ inp_pb) {
  const int b = blockIdx.x, t = threadIdx.x;
  __shared__ float xs[D_];
  xs[t] = x[b * D_ + t];
  xs[t + 256] = x[b * D_ + t + 256];
  __syncthreads();
  for (int h = t; h < H_; h += 256) {
    const float4* wr = (const float4*)(W_in + (size_t)h * D_);
    float acc = 0.f;
#pragma unroll 4
    for (int d4 = 0; d4 < 128; ++d4) {
      float4 w = wr[d4];
      acc += w.x * xs[d4 * 4] + w.y * xs[d4 * 4 + 1] + w.z * xs[d4 * 4 + 2] +
             w.w * xs[d4 * 4 + 3];
    }
    inp_pb[b * H_ + h] = acc + b_in[h] + b_ctx[h];
  }
}

// ---------------- main path: att via MFMA, NO LDS staging, NO K-loop barriers ----
// 512 threads / 8 waves; wave owns 64 h x 64 s. Both A (Wc) and B (ctx16)
// fragments loaded directly from global (L2-served: Wc is 512KB hot; the 64KB
// ctx tile is shared by the WG's 8 waves on one CU). All loads use 8 hoisted
// base addresses + immediate offsets; barrier-free loop lets the compiler
// software-pipeline with counted vmcnt.
__global__ __launch_bounds__(512, 4) void k_att(
    const unsigned short* __restrict__ ctx16, const unsigned short* __restrict__ Wc,
    const float* __restrict__ inp_pb, const float* __restrict__ V,
    float* __restrict__ att) {
  __shared__ float red[8][64];
  const int tid = threadIdx.x;
  const int wave = tid >> 6, lane = tid & 63;
  const int b = blockIdx.y, s0 = blockIdx.x * 64;
  const int hbase = wave * 64;
  const int bln = lane & 15, blh = lane >> 4;

  const unsigned short* ab = Wc + (size_t)(hbase + bln) * D_ + blh * 8;
  const unsigned short* bb = ctx16 + ((size_t)b * S_ + s0 + bln) * D_ + blh * 8;

  f32x4 acc[4][4];
#pragma unroll
  for (int m = 0; m < 4; ++m)
#pragma unroll
    for (int n = 0; n < 4; ++n) acc[m][n] = f32x4{0.f, 0.f, 0.f, 0.f};

#pragma unroll
  for (int kk = 0; kk < 16; ++kk) {  // K = 16 * 32
    s16x8 afrag[4], bfrag[4];
#pragma unroll
    for (int m = 0; m < 4; ++m)
      afrag[m] = *(const s16x8*)(ab + (size_t)m * 16 * D_ + kk * 32);
#pragma unroll
    for (int n = 0; n < 4; ++n)
      bfrag[n] = *(const s16x8*)(bb + (size_t)n * 16 * D_ + kk * 32);
#pragma unroll
    for (int m = 0; m < 4; ++m)
#pragma unroll
      for (int n = 0; n < 4; ++n)
        acc[m][n] = __builtin_amdgcn_mfma_f32_16x16x32_bf16(afrag[m], bfrag[n],
                                                            acc[m][n], 0, 0, 0);
  }

  // epilogue: tanh + V-dot, reduce over h
  float attp[4] = {0.f, 0.f, 0.f, 0.f};
  const float* ib = inp_pb + b * H_;
#pragma unroll
  for (int m = 0; m < 4; ++m) {
#pragma unroll
    for (int j = 0; j < 4; ++j) {
      int h = hbase + m * 16 + (blh << 2) + j;
      float c = ib[h];
      float vh = V[h];
#pragma unroll
      for (int n = 0; n < 4; ++n) {
        float x = acc[m][n][j] + c;
        x = fminf(fmaxf(x, -15.f), 15.f);
        float e = __expf(2.f * x);
        attp[n] += vh * __fdividef(e - 1.f, e + 1.f);
      }
    }
  }
#pragma unroll
  for (int n = 0; n < 4; ++n) {
    attp[n] += __shfl_xor(attp[n], 16, 64);
    attp[n] += __shfl_xor(attp[n], 32, 64);
  }
  if (lane < 16) {
#pragma unroll
    for (int n = 0; n < 4; ++n) red[wave][n * 16 + lane] = attp[n];
  }
  __syncthreads();
  if (tid < 64) {
    float s = 0.f;
#pragma unroll
    for (int w = 0; w < 8; ++w) s += red[w][tid];
    att[(size_t)b * S_ + s0 + tid] = s;
  }
}

// ---------------- fallback k_att (f32 context, reg-staged) ----------------
__global__ __launch_bounds__(512, 4) void k_att_f32(
    const float* __restrict__ context, const unsigned short* __restrict__ Wc,
    const float* __restrict__ inp_pb, const float* __restrict__ V,
    float* __restrict__ att) {
  __shared__ char lds[8192];
  __shared__ float red[8][64];
  const int tid = threadIdx.x;
  const int wave = tid >> 6, lane = tid & 63;
  const int b = blockIdx.y, s0 = blockIdx.x * 64;
  const float* ctxb = context + ((size_t)b * S_ + s0) * D_;
  const int hbase = wave * 64;
  const int srow = tid >> 3;
  const int kc8 = (tid & 7) * 8;
  const int sbyte = (srow * 128 + kc8 * 2) ^ ((srow & 7) << 4);

  f32x4 acc[4][4];
#pragma unroll
  for (int m = 0; m < 4; ++m)
#pragma unroll
    for (int n = 0; n < 4; ++n) acc[m][n] = f32x4{0.f, 0.f, 0.f, 0.f};

  float4 stg0, stg1;
  auto load_tile = [&](int kc) {
    const float* p = ctxb + (size_t)srow * D_ + kc + kc8;
    stg0 = *(const float4*)p;
    stg1 = *(const float4*)(p + 4);
  };
  auto write_tile = [&]() {
    s16x8 hb;
    hb[0] = (short)f2bf(stg0.x); hb[1] = (short)f2bf(stg0.y);
    hb[2] = (short)f2bf(stg0.z); hb[3] = (short)f2bf(stg0.w);
    hb[4] = (short)f2bf(stg1.x); hb[5] = (short)f2bf(stg1.y);
    hb[6] = (short)f2bf(stg1.z); hb[7] = (short)f2bf(stg1.w);
    *(s16x8*)(lds + sbyte) = hb;
  };

  load_tile(0);
  write_tile();
  __syncthreads();

  const int bln = lane & 15, blh = lane >> 4;
  for (int t = 0; t < 8; ++t) {
    if (t < 7) load_tile((t + 1) * 64);
    const int kc0 = t * 64;
#pragma unroll
    for (int kk = 0; kk < 2; ++kk) {
      s16x8 bfrag[4];
#pragma unroll
      for (int n = 0; n < 4; ++n) {
        int s = n * 16 + bln;
        int byte = (s * 128 + kk * 64 + (blh << 4)) ^ ((s & 7) << 4);
        bfrag[n] = *(const s16x8*)(lds + byte);
      }
      s16x8 afrag[4];
#pragma unroll
      for (int m = 0; m < 4; ++m) {
        int h = hbase + m * 16 + bln;
        int k = kc0 + kk * 32 + (blh << 3);
        afrag[m] = *(const s16x8*)(Wc + (size_t)h * D_ + k);
      }
#pragma unroll
      for (int m = 0; m < 4; ++m)
#pragma unroll
        for (int n = 0; n < 4; ++n)
          acc[m][n] = __builtin_amdgcn_mfma_f32_16x16x32_bf16(afrag[m], bfrag[n],
                                                              acc[m][n], 0, 0, 0);
    }
    __syncthreads();
    if (t < 7) write_tile();
    __syncthreads();
  }

  float attp[4] = {0.f, 0.f, 0.f, 0.f};
  const float* ib = inp_pb + b * H_;
#pragma unroll
  for (int m = 0; m < 4; ++m) {
#pragma unroll
    for (int j = 0; j < 4; ++j) {
      int h = hbase + m * 16 + (blh << 2) + j;
      float c = ib[h];
      float vh = V[h];
#pragma unroll
      for (int n = 0; n < 4; ++n) {
        float x = acc[m][n][j] + c;
        x = fminf(fmaxf(x, -15.f), 15.f);
        float e = __expf(2.f * x);
        attp[n] += vh * __fdividef(e - 1.f, e + 1.f);
      }
    }
  }
#pragma unroll
  for (int n = 0; n < 4; ++n) {
    attp[n] += __shfl_xor(attp[n], 16, 64);
    attp[n] += __shfl_xor(attp[n], 32, 64);
  }
  if (lane < 16) {
#pragma unroll
    for (int n = 0; n < 4; ++n) red[wave][n * 16 + lane] = attp[n];
  }
  __syncthreads();
  if (tid < 64) {
    float s = 0.f;
#pragma unroll
    for (int w = 0; w < 8; ++w) s += red[w][tid];
    att[(size_t)b * S_ + s0 + tid] = s;
  }
}

// ---------------- masked softmax over S -> alpha ----------------
__global__ void k_softmax(const float* __restrict__ att, const void* __restrict__ mask,
                          const int* __restrict__ flag, float* __restrict__ alpha) {
  const int b = blockIdx.x, t = threadIdx.x;
  const int c = *flag;
  const int mtype = (c & 2) ? 2 : (c & 1);  // 2=float, 1=bytes, 0=int32
  __shared__ float sm[4];
  const unsigned char* m8 = (const unsigned char*)mask;
  const int* m32 = (const int*)mask;
  const float* mf = (const float*)mask;
  float vals[8];
  float mx = -3.0e38f;
#pragma unroll
  for (int i = 0; i < 8; ++i) {
    int s = t + i * 256;
    size_t idx = (size_t)b * S_ + s;
    int msk = (mtype == 1) ? (int)m8[idx] : (mtype == 2) ? (mf[idx] != 0.f) : m32[idx];
    float v = msk ? -__builtin_inff() : att[idx];
    vals[i] = v;
    mx = fmaxf(mx, v);
  }
  for (int off = 32; off; off >>= 1) mx = fmaxf(mx, __shfl_xor(mx, off, 64));
  if ((t & 63) == 0) sm[t >> 6] = mx;
  __syncthreads();
  mx = fmaxf(fmaxf(sm[0], sm[1]), fmaxf(sm[2], sm[3]));
  float es[8];
  float sum = 0.f;
#pragma unroll
  for (int i = 0; i < 8; ++i) {
    es[i] = __expf(vals[i] - mx);
    sum += es[i];
  }
  for (int off = 32; off; off >>= 1) sum += __shfl_xor(sum, off, 64);
  __syncthreads();
  if ((t & 63) == 0) sm[t >> 6] = sum;
  __syncthreads();
  sum = sm[0] + sm[1] + sm[2] + sm[3];
  float inv = __fdividef(1.f, sum);
#pragma unroll
  for (int i = 0; i < 8; ++i) alpha[(size_t)b * S_ + t + i * 256] = es[i] * inv;
}

// ---------------- y partials from bf16 context ----------------
__global__ __launch_bounds__(256) void k_ypart(const unsigned short* __restrict__ ctx16,
                                               const float* __restrict__ alpha,
                                               float* __restrict__ y_part) {
  const int chunk = blockIdx.x, b = blockIdx.y, t = threadIdx.x;
  const int g = t >> 6, lane = t & 63;
  __shared__ float al[256];
  __shared__ float part[3][512];
  al[t] = alpha[(size_t)b * S_ + chunk * 256 + t];
  __syncthreads();
  float a8[8];
#pragma unroll
  for (int j = 0; j < 8; ++j) a8[j] = 0.f;
  const unsigned short* base =
      ctx16 + ((size_t)b * S_ + chunk * 256) * D_ + lane * 8;
  for (int i = 0; i < 64; ++i) {
    int s = g * 64 + i;
    u16x8 v = *(const u16x8*)(base + (size_t)s * D_);
    float a = al[s];
#pragma unroll
    for (int j = 0; j < 8; ++j) a8[j] += a * bf2f(v[j]);
  }
  if (g > 0) {
#pragma unroll
    for (int j = 0; j < 8; ++j) part[g - 1][lane * 8 + j] = a8[j];
  }
  __syncthreads();
  if (g == 0) {
#pragma unroll
    for (int j = 0; j < 8; ++j) {
      float s = a8[j] + part[0][lane * 8 + j] + part[1][lane * 8 + j] +
                part[2][lane * 8 + j];
      y_part[((size_t)(b * 8 + chunk)) * D_ + lane * 8 + j] = s;
    }
  }
}

// ---------------- fallback y partials (f32 context) ----------------
__global__ void k_ypart_f32(const float* __restrict__ context,
                            const float* __restrict__ alpha, float* __restrict__ y_part) {
  const int chunk = blockIdx.x, b = blockIdx.y, t = threadIdx.x;
  __shared__ float al[256];
  __shared__ float4 part[128];
  al[t] = alpha[(size_t)b * S_ + chunk * 256 + t];
  __syncthreads();
  const int d4 = t & 127, sr = t >> 7;
  const float4* base = (const float4*)(context + ((size_t)b * S_ + chunk * 256) * D_);
  float4 acc = make_float4(0.f, 0.f, 0.f, 0.f);
  for (int i = 0; i < 128; ++i) {
    int s = sr + 2 * i;
    float4 v = base[(size_t)s * 128 + d4];
    float a = al[s];
    acc.x += a * v.x; acc.y += a * v.y; acc.z += a * v.z; acc.w += a * v.w;
  }
  if (sr == 1) part[d4] = acc;
  __syncthreads();
  if (sr == 0) {
    float4 o = part[d4];
    o.x += acc.x; o.y += acc.y; o.z += acc.z; o.w += acc.w;
    *(float4*)(y_part + ((size_t)(b * 8 + chunk)) * D_ + d4 * 4) = o;
  }
}

// ---------------- hidden = W_ctx @ y + b_ctx (exact f32) ----------------
__global__ void k_hidden(const float* __restrict__ y_part, const float* __restrict__ W_ctx,
                         const float* __restrict__ b_ctx, float* __restrict__ hidden) {
  const int b = blockIdx.x, t = threadIdx.x;
  __shared__ float ys[D_];
  for (int d = t; d < D_; d += 256) {
    float s = 0.f;
#pragma unroll
    for (int c = 0; c < 8; ++c) s += y_part[((size_t)(b * 8 + c)) * D_ + d];
    ys[d] = s;
  }
  __syncthreads();
  for (int h = t; h < H_; h += 256) {
    const float4* wr = (const float4*)(W_ctx + (size_t)h * D_);
    float acc = 0.f;
#pragma unroll 4
    for (int d4 = 0; d4 < 128; ++d4) {
      float4 w = wr[d4];
      acc += w.x * ys[d4 * 4] + w.y * ys[d4 * 4 + 1] + w.z * ys[d4 * 4 + 2] +
             w.w * ys[d4 * 4 + 3];
    }
    hidden[b * H_ + h] = acc + b_ctx[h];
  }
}

extern "C" void kernel_launch(void* const* d_in, const int* in_sizes, int n_in,
                              void* d_out, int out_size, void* d_ws, size_t ws_size,
                              hipStream_t stream) {
  (void)in_sizes; (void)n_in; (void)out_size;
  const float* x = (const float*)d_in[0];
  const float* context = (const float*)d_in[1];
  const void* mask = d_in[2];
  const float* W_in = (const float*)d_in[3];
  const float* b_in = (const float*)d_in[4];
  const float* W_ctx = (const float*)d_in[5];
  const float* b_ctx = (const float*)d_in[6];
  const float* V = (const float*)d_in[7];

  float* out_hidden = (float*)d_out;           // [B,H]
  float* out_alpha = (float*)d_out + B_ * H_;  // [B,S]

  // workspace layout (bytes): inp_pb 128K | att 512K | y_part 1M | flag 64 |
  // Wb 512K | ctx16 134M
  char* ws = (char*)d_ws;
  float* inp_pb = (float*)ws;                       // B*H f32
  float* att = (float*)(ws + 131072);               // B*S f32
  float* y_part = (float*)(ws + 655360);            // B*8*D f32
  int* flag = (int*)(ws + 1703936);                 // 16 ints
  unsigned short* Wb = (unsigned short*)(ws + 1704000);  // H*D bf16
  unsigned short* ctx16 = (unsigned short*)(ws + 2228288);  // B*S*D bf16
  const size_t need = 2228288 + (size_t)B_ * S_ * D_ * 2;
  const bool big_ws = (ws_size >= need);

  k_zero<<<1, 64, 0, stream>>>(flag);
  k_detect<<<128, 256, 0, stream>>>((const unsigned int*)mask, flag);
  k_cvt<<<(H_ * D_) / (256 * 8), 256, 0, stream>>>(W_ctx, Wb);
  k_inp<<<B_, 256, 0, stream>>>(x, W_in, b_in, b_ctx, inp_pb);
  if (big_ws) {
    k_cvtctx<<<2048, 256, 0, stream>>>(context, ctx16);
    k_att<<<dim3(S_ / 64, B_), 512, 0, stream>>>(ctx16, Wb, inp_pb, V, att);
    k_softmax<<<B_, 256, 0, stream>>>(att, mask, flag, out_alpha);
    k_ypart<<<dim3(8, B_), 256, 0, stream>>>(ctx16, out_alpha, y_part);
  } else {
    k_att_f32<<<dim3(S_ / 64, B_), 512, 0, stream>>>(context, Wb, inp_pb, V, att);
    k_softmax<<<B_, 256, 0, stream>>>(att, mask, flag, out_alpha);
    k_ypart_f32<<<dim3(8, B_), 256, 0, stream>>>(context, out_alpha, y_part);
  }
  k_hidden<<<B_, 256, 0, stream>>>(y_part, W_ctx, b_ctx, out_hidden);
}

// Round 6
// 323.839 us; speedup vs baseline: 1.3318x; 1.3318x over previous
//
#include <hip/hip_runtime.h>
#include <hip/hip_bf16.h>
#include <cstdint>

#define B_ 64
#define S_ 2048
#define D_ 512
#define H_ 512

typedef short s16x8 __attribute__((ext_vector_type(8)));
typedef float f32x4 __attribute__((ext_vector_type(4)));

static __device__ __forceinline__ unsigned short f2bf(float f) {
  __bf16 h = (__bf16)f;
  return __builtin_bit_cast(unsigned short, h);
}
static __device__ __forceinline__ void gld_lds16(const void* g, void* l) {
  __builtin_amdgcn_global_load_lds((__attribute__((address_space(1))) void*)(g),
                                   (__attribute__((address_space(3))) void*)(l),
                                   16, 0, 0);
}

#define VM_WAIT_2  asm volatile("s_waitcnt vmcnt(2)" ::: "memory")
#define VM_WAIT_8  asm volatile("s_waitcnt vmcnt(8)" ::: "memory")
#define VM_WAIT_10 asm volatile("s_waitcnt vmcnt(10)" ::: "memory")

// ---------------- mask dtype detection (parallel) ----------------
__global__ void k_zero(int* __restrict__ flag) {
  if (threadIdx.x == 0) *flag = 0;
}
__global__ void k_detect(const unsigned int* __restrict__ mw, int* __restrict__ flag) {
  int i = blockIdx.x * 256 + threadIdx.x;  // 128 blocks x 256 = 32768
  unsigned w = mw[i];
  int bits = 0;
  if (w == 0x3F800000u) bits = 2;
  else if (w > 1u) bits = 1;
  unsigned long long a1 = __ballot(bits & 1);
  unsigned long long a2 = __ballot(bits & 2);
  if ((threadIdx.x & 63) == 0) {
    int v = (a1 ? 1 : 0) | (a2 ? 2 : 0);
    if (v) atomicOr(flag, v);
  }
}

// ---------------- W_ctx f32 -> bf16 ----------------
__global__ void k_cvt(const float* __restrict__ W, unsigned short* __restrict__ Wb) {
  int i = (blockIdx.x * 256 + threadIdx.x) * 8;
  float4 a = *(const float4*)(W + i);
  float4 c = *(const float4*)(W + i + 4);
  ushort4 o0 = make_ushort4(f2bf(a.x), f2bf(a.y), f2bf(a.z), f2bf(a.w));
  ushort4 o1 = make_ushort4(f2bf(c.x), f2bf(c.y), f2bf(c.z), f2bf(c.w));
  *(ushort4*)(Wb + i) = o0;
  *(ushort4*)(Wb + i + 4) = o1;
}

// ---------------- inp' = x @ W_in^T + b_in + b_ctx ----------------
__global__ void k_inp(const float* __restrict__ x, const float* __restrict__ W_in,
                      const float* __restrict__ b_in, const float* __restrict__ b_ctx,
                      float* __restrict__ inp_pb) {
  const int b = blockIdx.x, t = threadIdx.x;
  __shared__ float xs[D_];
  xs[t] = x[b * D_ + t];
  xs[t + 256] = x[b * D_ + t + 256];
  __syncthreads();
  for (int h = t; h < H_; h += 256) {
    const float4* wr = (const float4*)(W_in + (size_t)h * D_);
    float acc = 0.f;
#pragma unroll 4
    for (int d4 = 0; d4 < 128; ++d4) {
      float4 w = wr[d4];
      acc += w.x * xs[d4 * 4] + w.y * xs[d4 * 4 + 1] + w.z * xs[d4 * 4 + 2] +
             w.w * xs[d4 * 4 + 3];
    }
    inp_pb[b * H_ + h] = acc + b_in[h] + b_ctx[h];
  }
}

// ---------------- att[b,s] = sum_h V[h]*tanh(inp'[b,h] + (W_ctx@ctx^T)[h,s]) ----
// 512 thr / 8 waves; wave = 64h x 64s (acc[4][4]). B-tile = 64s x 64k f32
// staged direct from context via global_load_lds into 3 rotating 16KB LDS
// buffers, 2 tiles in flight across raw s_barrier with counted vmcnt (never 0
// in-loop). A-frags (bf16 Wc) direct from L2. XOR-swizzle (s&7)<<5 applied on
// the global source and the ds_read side (rule #21: both-sides-or-neither).
// Per-iter VMEM order is exactly [afrag x8, gld_lds x2] so in-order vmcnt
// arithmetic gives: wait(t=0)=2, wait(t=7)=8, else 10.
__global__ __launch_bounds__(512, 3) void k_att(
    const float* __restrict__ context, const unsigned short* __restrict__ Wc,
    const float* __restrict__ inp_pb, const float* __restrict__ V,
    float* __restrict__ att) {
  __shared__ char bt[3][16384];  // [s 64][k 64] f32, row 256B, swizzled
  __shared__ float red[8][64];
  const int tid = threadIdx.x;
  const int wave = tid >> 6, lane = tid & 63;
  const int b = blockIdx.y, s0 = blockIdx.x * 64;
  const float* ctxb = context + ((size_t)b * S_ + s0) * D_;
  const int hbase = wave * 64;
  const int bln = lane & 15, blh = lane >> 4;

  // staging geometry: wave stages rows [8w, 8w+8) as 2 gld_lds of 1KB.
  // gld_lds j covers rows 8w+4j+(lane>>4); lane writes 16B at (lane&15)*16
  // within the 256B row (linear dest). Global src pre-applies the inverse
  // swizzle so that read-side XOR recovers linear k.
  const int r0 = wave * 8 + (lane >> 4);
  const int r1 = r0 + 4;
  const int po = (lane & 15) * 16;
  const float* g0 = ctxb + (size_t)r0 * D_ + ((po ^ ((r0 & 7) << 5)) >> 2);
  const float* g1 = ctxb + (size_t)r1 * D_ + ((po ^ ((r1 & 7) << 5)) >> 2);
  const int ldso = wave * 2048;

  f32x4 acc[4][4];
#pragma unroll
  for (int m = 0; m < 4; ++m)
#pragma unroll
    for (int n = 0; n < 4; ++n) acc[m][n] = f32x4{0.f, 0.f, 0.f, 0.f};

  // prologue: tiles 0,1 in flight
  gld_lds16(g0, &bt[0][ldso]);
  gld_lds16(g1, &bt[0][ldso + 1024]);
  gld_lds16(g0 + 64, &bt[1][ldso]);
  gld_lds16(g1 + 64, &bt[1][ldso + 1024]);

#pragma unroll
  for (int t = 0; t < 8; ++t) {
    if (t == 0) { VM_WAIT_2; } else if (t == 7) { VM_WAIT_8; } else { VM_WAIT_10; }
    __builtin_amdgcn_s_barrier();
    __builtin_amdgcn_sched_barrier(0);

    // A fragments for this iter (8 x 16B from L2)
    s16x8 af[2][4];
#pragma unroll
    for (int kk = 0; kk < 2; ++kk)
#pragma unroll
      for (int m = 0; m < 4; ++m)
        af[kk][m] = *(const s16x8*)(Wc + (size_t)(hbase + m * 16 + bln) * D_ +
                                    t * 64 + kk * 32 + blh * 8);

    if (t < 6) {  // prefetch tile t+2 into buf (t+2)%3 (freed at this barrier)
      const int nb = (t + 2) % 3;
      gld_lds16(g0 + (t + 2) * 64, &bt[nb][ldso]);
      gld_lds16(g1 + (t + 2) * 64, &bt[nb][ldso + 1024]);
    }

    const char* cb = bt[t % 3];
#pragma unroll
    for (int kk = 0; kk < 2; ++kk) {
#pragma unroll
      for (int n = 0; n < 4; ++n) {
        const int sr = n * 16 + bln;
        const int phys = (kk * 128 + blh * 32) ^ ((sr & 7) << 5);
        const float* p = (const float*)(cb + sr * 256 + phys);
        f32x4 lo = *(const f32x4*)p;
        f32x4 hi = *(const f32x4*)(p + 4);
        s16x8 bf;
        bf[0] = (short)f2bf(lo[0]); bf[1] = (short)f2bf(lo[1]);
        bf[2] = (short)f2bf(lo[2]); bf[3] = (short)f2bf(lo[3]);
        bf[4] = (short)f2bf(hi[0]); bf[5] = (short)f2bf(hi[1]);
        bf[6] = (short)f2bf(hi[2]); bf[7] = (short)f2bf(hi[3]);
#pragma unroll
        for (int m = 0; m < 4; ++m)
          acc[m][n] = __builtin_amdgcn_mfma_f32_16x16x32_bf16(af[kk][m], bf,
                                                              acc[m][n], 0, 0, 0);
      }
    }
  }

  // epilogue: tanh + V-dot, reduce over h
  float attp[4] = {0.f, 0.f, 0.f, 0.f};
  const float* ib = inp_pb + b * H_;
#pragma unroll
  for (int m = 0; m < 4; ++m) {
#pragma unroll
    for (int j = 0; j < 4; ++j) {
      int h = hbase + m * 16 + (blh << 2) + j;
      float c = ib[h];
      float vh = V[h];
#pragma unroll
      for (int n = 0; n < 4; ++n) {
        float x = acc[m][n][j] + c;
        x = fminf(fmaxf(x, -15.f), 15.f);
        float e = __expf(2.f * x);
        attp[n] += vh * __fdividef(e - 1.f, e + 1.f);
      }
    }
  }
#pragma unroll
  for (int n = 0; n < 4; ++n) {
    attp[n] += __shfl_xor(attp[n], 16, 64);
    attp[n] += __shfl_xor(attp[n], 32, 64);
  }
  if (lane < 16) {
#pragma unroll
    for (int n = 0; n < 4; ++n) red[wave][n * 16 + lane] = attp[n];
  }
  __syncthreads();
  if (tid < 64) {
    float s = 0.f;
#pragma unroll
    for (int w = 0; w < 8; ++w) s += red[w][tid];
    att[(size_t)b * S_ + s0 + tid] = s;
  }
}

// ---------------- masked softmax over S -> alpha ----------------
__global__ void k_softmax(const float* __restrict__ att, const void* __restrict__ mask,
                          const int* __restrict__ flag, float* __restrict__ alpha) {
  const int b = blockIdx.x, t = threadIdx.x;
  const int c = *flag;
  const int mtype = (c & 2) ? 2 : (c & 1);  // 2=float, 1=bytes, 0=int32
  __shared__ float sm[4];
  const unsigned char* m8 = (const unsigned char*)mask;
  const int* m32 = (const int*)mask;
  const float* mf = (const float*)mask;
  float vals[8];
  float mx = -3.0e38f;
#pragma unroll
  for (int i = 0; i < 8; ++i) {
    int s = t + i * 256;
    size_t idx = (size_t)b * S_ + s;
    int msk = (mtype == 1) ? (int)m8[idx] : (mtype == 2) ? (mf[idx] != 0.f) : m32[idx];
    float v = msk ? -__builtin_inff() : att[idx];
    vals[i] = v;
    mx = fmaxf(mx, v);
  }
  for (int off = 32; off; off >>= 1) mx = fmaxf(mx, __shfl_xor(mx, off, 64));
  if ((t & 63) == 0) sm[t >> 6] = mx;
  __syncthreads();
  mx = fmaxf(fmaxf(sm[0], sm[1]), fmaxf(sm[2], sm[3]));
  float es[8];
  float sum = 0.f;
#pragma unroll
  for (int i = 0; i < 8; ++i) {
    es[i] = __expf(vals[i] - mx);
    sum += es[i];
  }
  for (int off = 32; off; off >>= 1) sum += __shfl_xor(sum, off, 64);
  __syncthreads();
  if ((t & 63) == 0) sm[t >> 6] = sum;
  __syncthreads();
  sum = sm[0] + sm[1] + sm[2] + sm[3];
  float inv = __fdividef(1.f, sum);
#pragma unroll
  for (int i = 0; i < 8; ++i) alpha[(size_t)b * S_ + t + i * 256] = es[i] * inv;
}

// ---------------- y partials: y[b,d] = sum_s alpha*context (f32) ----------------
__global__ void k_ypart(const float* __restrict__ context,
                        const float* __restrict__ alpha, float* __restrict__ y_part) {
  const int chunk = blockIdx.x, b = blockIdx.y, t = threadIdx.x;
  __shared__ float al[256];
  __shared__ float4 part[128];
  al[t] = alpha[(size_t)b * S_ + chunk * 256 + t];
  __syncthreads();
  const int d4 = t & 127, sr = t >> 7;
  const float4* base = (const float4*)(context + ((size_t)b * S_ + chunk * 256) * D_);
  float4 acc = make_float4(0.f, 0.f, 0.f, 0.f);
  for (int i = 0; i < 128; ++i) {
    int s = sr + 2 * i;
    float4 v = base[(size_t)s * 128 + d4];
    float a = al[s];
    acc.x += a * v.x; acc.y += a * v.y; acc.z += a * v.z; acc.w += a * v.w;
  }
  if (sr == 1) part[d4] = acc;
  __syncthreads();
  if (sr == 0) {
    float4 o = part[d4];
    o.x += acc.x; o.y += acc.y; o.z += acc.z; o.w += acc.w;
    *(float4*)(y_part + ((size_t)(b * 8 + chunk)) * D_ + d4 * 4) = o;
  }
}

// ---------------- hidden = W_ctx @ y + b_ctx (exact f32) ----------------
__global__ void k_hidden(const float* __restrict__ y_part, const float* __restrict__ W_ctx,
                         const float* __restrict__ b_ctx, float* __restrict__ hidden) {
  const int b = blockIdx.x, t = threadIdx.x;
  __shared__ float ys[D_];
  for (int d = t; d < D_; d += 256) {
    float s = 0.f;
#pragma unroll
    for (int c = 0; c < 8; ++c) s += y_part[((size_t)(b * 8 + c)) * D_ + d];
    ys[d] = s;
  }
  __syncthreads();
  for (int h = t; h < H_; h += 256) {
    const float4* wr = (const float4*)(W_ctx + (size_t)h * D_);
    float acc = 0.f;
#pragma unroll 4
    for (int d4 = 0; d4 < 128; ++d4) {
      float4 w = wr[d4];
      acc += w.x * ys[d4 * 4] + w.y * ys[d4 * 4 + 1] + w.z * ys[d4 * 4 + 2] +
             w.w * ys[d4 * 4 + 3];
    }
    hidden[b * H_ + h] = acc + b_ctx[h];
  }
}

extern "C" void kernel_launch(void* const* d_in, const int* in_sizes, int n_in,
                              void* d_out, int out_size, void* d_ws, size_t ws_size,
                              hipStream_t stream) {
  (void)in_sizes; (void)n_in; (void)out_size; (void)ws_size;
  const float* x = (const float*)d_in[0];
  const float* context = (const float*)d_in[1];
  const void* mask = d_in[2];
  const float* W_in = (const float*)d_in[3];
  const float* b_in = (const float*)d_in[4];
  const float* W_ctx = (const float*)d_in[5];
  const float* b_ctx = (const float*)d_in[6];
  const float* V = (const float*)d_in[7];

  float* out_hidden = (float*)d_out;           // [B,H]
  float* out_alpha = (float*)d_out + B_ * H_;  // [B,S]

  // workspace: inp_pb 128K | att 512K | y_part 1M | flag | Wb 512K
  char* ws = (char*)d_ws;
  float* inp_pb = (float*)ws;                            // B*H f32
  float* att = (float*)(ws + 131072);                    // B*S f32
  float* y_part = (float*)(ws + 655360);                 // B*8*D f32
  int* flag = (int*)(ws + 1703936);                      // 16 ints
  unsigned short* Wb = (unsigned short*)(ws + 1704000);  // H*D bf16

  k_zero<<<1, 64, 0, stream>>>(flag);
  k_detect<<<128, 256, 0, stream>>>((const unsigned int*)mask, flag);
  k_cvt<<<(H_ * D_) / (256 * 8), 256, 0, stream>>>(W_ctx, Wb);
  k_inp<<<B_, 256, 0, stream>>>(x, W_in, b_in, b_ctx, inp_pb);
  k_att<<<dim3(S_ / 64, B_), 512, 0, stream>>>(context, Wb, inp_pb, V, att);
  k_softmax<<<B_, 256, 0, stream>>>(att, mask, flag, out_alpha);
  k_ypart<<<dim3(8, B_), 256, 0, stream>>>(context, out_alpha, y_part);
  k_hidden<<<B_, 256, 0, stream>>>(y_part, W_ctx, b_ctx, out_hidden);
}

// Round 7
// 288.079 us; speedup vs baseline: 1.4971x; 1.1241x over previous
//
#include <hip/hip_runtime.h>
#include <hip/hip_bf16.h>
#include <cstdint>

#define B_ 64
#define S_ 2048
#define D_ 512
#define H_ 512

typedef short s16x8 __attribute__((ext_vector_type(8)));
typedef float f32x4 __attribute__((ext_vector_type(4)));

static __device__ __forceinline__ unsigned short f2bf(float f) {
  __bf16 h = (__bf16)f;
  return __builtin_bit_cast(unsigned short, h);
}

// ---------------- mask dtype detection (parallel) ----------------
__global__ void k_zero(int* __restrict__ flag) {
  if (threadIdx.x == 0) *flag = 0;
}
__global__ void k_detect(const unsigned int* __restrict__ mw, int* __restrict__ flag) {
  int i = blockIdx.x * 256 + threadIdx.x;  // 128 blocks x 256 = 32768
  unsigned w = mw[i];
  int bits = 0;
  if (w == 0x3F800000u) bits = 2;
  else if (w > 1u) bits = 1;
  unsigned long long a1 = __ballot(bits & 1);
  unsigned long long a2 = __ballot(bits & 2);
  if ((threadIdx.x & 63) == 0) {
    int v = (a1 ? 1 : 0) | (a2 ? 2 : 0);
    if (v) atomicOr(flag, v);
  }
}

// ---------------- W_ctx f32 -> bf16 ----------------
__global__ void k_cvt(const float* __restrict__ W, unsigned short* __restrict__ Wb) {
  int i = (blockIdx.x * 256 + threadIdx.x) * 8;
  float4 a = *(const float4*)(W + i);
  float4 c = *(const float4*)(W + i + 4);
  ushort4 o0 = make_ushort4(f2bf(a.x), f2bf(a.y), f2bf(a.z), f2bf(a.w));
  ushort4 o1 = make_ushort4(f2bf(c.x), f2bf(c.y), f2bf(c.z), f2bf(c.w));
  *(ushort4*)(Wb + i) = o0;
  *(ushort4*)(Wb + i + 4) = o1;
}

// ---------------- inp' = x @ W_in^T + b_in + b_ctx ----------------
__global__ void k_inp(const float* __restrict__ x, const float* __restrict__ W_in,
                      const float* __restrict__ b_in, const float* __restrict__ b_ctx,
                      float* __restrict__ inp_pb) {
  const int b = blockIdx.x, t = threadIdx.x;
  __shared__ float xs[D_];
  xs[t] = x[b * D_ + t];
  xs[t + 256] = x[b * D_ + t + 256];
  __syncthreads();
  for (int h = t; h < H_; h += 256) {
    const float4* wr = (const float4*)(W_in + (size_t)h * D_);
    float acc = 0.f;
#pragma unroll 4
    for (int d4 = 0; d4 < 128; ++d4) {
      float4 w = wr[d4];
      acc += w.x * xs[d4 * 4] + w.y * xs[d4 * 4 + 1] + w.z * xs[d4 * 4 + 2] +
             w.w * xs[d4 * 4 + 3];
    }
    inp_pb[b * H_ + h] = acc + b_in[h] + b_ctx[h];
  }
}

// ---------------- att[b,s] = sum_h V[h]*tanh(inp'[b,h] + (W_ctx@ctx^T)[h,s]) ----
// 512 thr / 8 waves; wave = 64h x 64s (acc[4][4]).
// Context staged with NON-TEMPORAL f32 loads (keeps Wc L2-resident), reg-cvt
// to bf16, write-late into double-buffered LDS (8KB/buf), 16B-granular XOR
// swizzle ((s&7)<<4) -> conflict-free ds_read_b128 AND ds_write_b128.
// A-frags (bf16 Wc, 512KB) direct from L2 (now unevicted). One barrier/iter.
__global__ __launch_bounds__(512, 2) void k_att(
    const float* __restrict__ context, const unsigned short* __restrict__ Wc,
    const float* __restrict__ inp_pb, const float* __restrict__ V,
    float* __restrict__ att) {
  __shared__ char bt[2][8192];  // [s 64][k 64] bf16, 128B rows, swizzled
  __shared__ float red[8][64];
  const int tid = threadIdx.x;
  const int wave = tid >> 6, lane = tid & 63;
  const int b = blockIdx.y, s0 = blockIdx.x * 64;
  const float* ctxb = context + ((size_t)b * S_ + s0) * D_;
  const int hbase = wave * 64;
  const int bln = lane & 15, blh = lane >> 4;

  // staging: thread -> row srow = tid>>3 (0..63), k-chunk (tid&7)*8
  const int srow = tid >> 3, kc8 = (tid & 7) * 8;
  const int sbyte = srow * 128 + ((kc8 * 2) ^ ((srow & 7) << 4));
  const float* gsrc = ctxb + (size_t)srow * D_ + kc8;

  f32x4 acc[4][4];
#pragma unroll
  for (int m = 0; m < 4; ++m)
#pragma unroll
    for (int n = 0; n < 4; ++n) acc[m][n] = f32x4{0.f, 0.f, 0.f, 0.f};

  f32x4 stg0, stg1;
  auto load_nt = [&](int t) {
    const f32x4* p = (const f32x4*)(gsrc + t * 64);
    stg0 = __builtin_nontemporal_load(p);
    stg1 = __builtin_nontemporal_load((const f32x4*)(gsrc + t * 64 + 4));
  };
  auto cvt_write = [&](int buf) {
    s16x8 hb;
    hb[0] = (short)f2bf(stg0[0]); hb[1] = (short)f2bf(stg0[1]);
    hb[2] = (short)f2bf(stg0[2]); hb[3] = (short)f2bf(stg0[3]);
    hb[4] = (short)f2bf(stg1[0]); hb[5] = (short)f2bf(stg1[1]);
    hb[6] = (short)f2bf(stg1[2]); hb[7] = (short)f2bf(stg1[3]);
    *(s16x8*)(&bt[buf][sbyte]) = hb;
  };

  load_nt(0);
  cvt_write(0);
  __syncthreads();

  for (int t = 0; t < 8; ++t) {
    if (t < 7) load_nt(t + 1);  // issue early; consumed after MFMAs (T14)
    const char* cur = bt[t & 1];
#pragma unroll
    for (int kk = 0; kk < 2; ++kk) {
      s16x8 bfrag[4], af[4];
#pragma unroll
      for (int n = 0; n < 4; ++n) {
        const int sr = n * 16 + bln;
        const int off = (kk * 64 + blh * 16) ^ ((sr & 7) << 4);
        bfrag[n] = *(const s16x8*)(cur + sr * 128 + off);
      }
#pragma unroll
      for (int m = 0; m < 4; ++m)
        af[m] = *(const s16x8*)(Wc + (size_t)(hbase + m * 16 + bln) * D_ +
                                t * 64 + kk * 32 + blh * 8);
#pragma unroll
      for (int m = 0; m < 4; ++m)
#pragma unroll
        for (int n = 0; n < 4; ++n)
          acc[m][n] = __builtin_amdgcn_mfma_f32_16x16x32_bf16(af[m], bfrag[n],
                                                              acc[m][n], 0, 0, 0);
    }
    if (t < 7) cvt_write((t + 1) & 1);  // other buffer; its readers synced at t-1
    __syncthreads();
  }

  // epilogue: tanh + V-dot, reduce over h
  float attp[4] = {0.f, 0.f, 0.f, 0.f};
  const float* ib = inp_pb + b * H_;
#pragma unroll
  for (int m = 0; m < 4; ++m) {
#pragma unroll
    for (int j = 0; j < 4; ++j) {
      int h = hbase + m * 16 + (blh << 2) + j;
      float c = ib[h];
      float vh = V[h];
#pragma unroll
      for (int n = 0; n < 4; ++n) {
        float x = acc[m][n][j] + c;
        x = fminf(fmaxf(x, -15.f), 15.f);
        float e = __expf(2.f * x);
        attp[n] += vh * __fdividef(e - 1.f, e + 1.f);
      }
    }
  }
#pragma unroll
  for (int n = 0; n < 4; ++n) {
    attp[n] += __shfl_xor(attp[n], 16, 64);
    attp[n] += __shfl_xor(attp[n], 32, 64);
  }
  if (lane < 16) {
#pragma unroll
    for (int n = 0; n < 4; ++n) red[wave][n * 16 + lane] = attp[n];
  }
  __syncthreads();
  if (tid < 64) {
    float s = 0.f;
#pragma unroll
    for (int w = 0; w < 8; ++w) s += red[w][tid];
    att[(size_t)b * S_ + s0 + tid] = s;
  }
}

// ---------------- masked softmax over S -> alpha ----------------
__global__ void k_softmax(const float* __restrict__ att, const void* __restrict__ mask,
                          const int* __restrict__ flag, float* __restrict__ alpha) {
  const int b = blockIdx.x, t = threadIdx.x;
  const int c = *flag;
  const int mtype = (c & 2) ? 2 : (c & 1);  // 2=float, 1=bytes, 0=int32
  __shared__ float sm[4];
  const unsigned char* m8 = (const unsigned char*)mask;
  const int* m32 = (const int*)mask;
  const float* mf = (const float*)mask;
  float vals[8];
  float mx = -3.0e38f;
#pragma unroll
  for (int i = 0; i < 8; ++i) {
    int s = t + i * 256;
    size_t idx = (size_t)b * S_ + s;
    int msk = (mtype == 1) ? (int)m8[idx] : (mtype == 2) ? (mf[idx] != 0.f) : m32[idx];
    float v = msk ? -__builtin_inff() : att[idx];
    vals[i] = v;
    mx = fmaxf(mx, v);
  }
  for (int off = 32; off; off >>= 1) mx = fmaxf(mx, __shfl_xor(mx, off, 64));
  if ((t & 63) == 0) sm[t >> 6] = mx;
  __syncthreads();
  mx = fmaxf(fmaxf(sm[0], sm[1]), fmaxf(sm[2], sm[3]));
  float es[8];
  float sum = 0.f;
#pragma unroll
  for (int i = 0; i < 8; ++i) {
    es[i] = __expf(vals[i] - mx);
    sum += es[i];
  }
  for (int off = 32; off; off >>= 1) sum += __shfl_xor(sum, off, 64);
  __syncthreads();
  if ((t & 63) == 0) sm[t >> 6] = sum;
  __syncthreads();
  sum = sm[0] + sm[1] + sm[2] + sm[3];
  float inv = __fdividef(1.f, sum);
#pragma unroll
  for (int i = 0; i < 8; ++i) alpha[(size_t)b * S_ + t + i * 256] = es[i] * inv;
}

// ---------------- y partials: y[b,d] = sum_s alpha*context (f32) ----------------
__global__ void k_ypart(const float* __restrict__ context,
                        const float* __restrict__ alpha, float* __restrict__ y_part) {
  const int chunk = blockIdx.x, b = blockIdx.y, t = threadIdx.x;
  __shared__ float al[256];
  __shared__ float4 part[128];
  al[t] = alpha[(size_t)b * S_ + chunk * 256 + t];
  __syncthreads();
  const int d4 = t & 127, sr = t >> 7;
  const float4* base = (const float4*)(context + ((size_t)b * S_ + chunk * 256) * D_);
  float4 acc = make_float4(0.f, 0.f, 0.f, 0.f);
  for (int i = 0; i < 128; ++i) {
    int s = sr + 2 * i;
    float4 v = base[(size_t)s * 128 + d4];
    float a = al[s];
    acc.x += a * v.x; acc.y += a * v.y; acc.z += a * v.z; acc.w += a * v.w;
  }
  if (sr == 1) part[d4] = acc;
  __syncthreads();
  if (sr == 0) {
    float4 o = part[d4];
    o.x += acc.x; o.y += acc.y; o.z += acc.z; o.w += acc.w;
    *(float4*)(y_part + ((size_t)(b * 8 + chunk)) * D_ + d4 * 4) = o;
  }
}

// ---------------- hidden = W_ctx @ y + b_ctx (exact f32) ----------------
__global__ void k_hidden(const float* __restrict__ y_part, const float* __restrict__ W_ctx,
                         const float* __restrict__ b_ctx, float* __restrict__ hidden) {
  const int b = blockIdx.x, t = threadIdx.x;
  __shared__ float ys[D_];
  for (int d = t; d < D_; d += 256) {
    float s = 0.f;
#pragma unroll
    for (int c = 0; c < 8; ++c) s += y_part[((size_t)(b * 8 + c)) * D_ + d];
    ys[d] = s;
  }
  __syncthreads();
  for (int h = t; h < H_; h += 256) {
    const float4* wr = (const float4*)(W_ctx + (size_t)h * D_);
    float acc = 0.f;
#pragma unroll 4
    for (int d4 = 0; d4 < 128; ++d4) {
      float4 w = wr[d4];
      acc += w.x * ys[d4 * 4] + w.y * ys[d4 * 4 + 1] + w.z * ys[d4 * 4 + 2] +
             w.w * ys[d4 * 4 + 3];
    }
    hidden[b * H_ + h] = acc + b_ctx[h];
  }
}

extern "C" void kernel_launch(void* const* d_in, const int* in_sizes, int n_in,
                              void* d_out, int out_size, void* d_ws, size_t ws_size,
                              hipStream_t stream) {
  (void)in_sizes; (void)n_in; (void)out_size; (void)ws_size;
  const float* x = (const float*)d_in[0];
  const float* context = (const float*)d_in[1];
  const void* mask = d_in[2];
  const float* W_in = (const float*)d_in[3];
  const float* b_in = (const float*)d_in[4];
  const float* W_ctx = (const float*)d_in[5];
  const float* b_ctx = (const float*)d_in[6];
  const float* V = (const float*)d_in[7];

  float* out_hidden = (float*)d_out;           // [B,H]
  float* out_alpha = (float*)d_out + B_ * H_;  // [B,S]

  // workspace: inp_pb 128K | att 512K | y_part 1M | flag | Wb 512K
  char* ws = (char*)d_ws;
  float* inp_pb = (float*)ws;                            // B*H f32
  float* att = (float*)(ws + 131072);                    // B*S f32
  float* y_part = (float*)(ws + 655360);                 // B*8*D f32
  int* flag = (int*)(ws + 1703936);                      // 16 ints
  unsigned short* Wb = (unsigned short*)(ws + 1704000);  // H*D bf16

  k_zero<<<1, 64, 0, stream>>>(flag);
  k_detect<<<128, 256, 0, stream>>>((const unsigned int*)mask, flag);
  k_cvt<<<(H_ * D_) / (256 * 8), 256, 0, stream>>>(W_ctx, Wb);
  k_inp<<<B_, 256, 0, stream>>>(x, W_in, b_in, b_ctx, inp_pb);
  k_att<<<dim3(S_ / 64, B_), 512, 0, stream>>>(context, Wb, inp_pb, V, att);
  k_softmax<<<B_, 256, 0, stream>>>(att, mask, flag, out_alpha);
  k_ypart<<<dim3(8, B_), 256, 0, stream>>>(context, out_alpha, y_part);
  k_hidden<<<B_, 256, 0, stream>>>(y_part, W_ctx, b_ctx, out_hidden);
}

// Round 8
// 246.566 us; speedup vs baseline: 1.7491x; 1.1684x over previous
//
#include <hip/hip_runtime.h>
#include <hip/hip_bf16.h>
#include <cstdint>

#define B_ 64
#define S_ 2048
#define D_ 512
#define H_ 512

typedef short s16x8 __attribute__((ext_vector_type(8)));
typedef float f32x4 __attribute__((ext_vector_type(4)));

static __device__ __forceinline__ unsigned short f2bf(float f) {
  __bf16 h = (__bf16)f;
  return __builtin_bit_cast(unsigned short, h);
}

// ---------------- mask dtype detection (parallel) ----------------
__global__ void k_zero(int* __restrict__ flag) {
  if (threadIdx.x == 0) *flag = 0;
}
__global__ void k_detect(const unsigned int* __restrict__ mw, int* __restrict__ flag) {
  int i = blockIdx.x * 256 + threadIdx.x;  // 128 blocks x 256 = 32768
  unsigned w = mw[i];
  int bits = 0;
  if (w == 0x3F800000u) bits = 2;
  else if (w > 1u) bits = 1;
  unsigned long long a1 = __ballot(bits & 1);
  unsigned long long a2 = __ballot(bits & 2);
  if ((threadIdx.x & 63) == 0) {
    int v = (a1 ? 1 : 0) | (a2 ? 2 : 0);
    if (v) atomicOr(flag, v);
  }
}

// ---------------- pack W_ctx into MFMA-fragment-major bf16 layout ----------------
// Wp[((kb*32 + hb)*64 + lane)*8 + e] = bf16(W_ctx[hb*16 + (lane&15)]
//                                               [kb*32 + (lane>>4)*8 + e])
// so an A-fragment load in k_att is base + lane*16B: one contiguous 1KB burst.
__global__ __launch_bounds__(256) void k_pack(const float* __restrict__ W,
                                              unsigned short* __restrict__ Wp) {
  const int tid = blockIdx.x * 256 + threadIdx.x;  // 128 blocks -> 32768 threads
  const int lane = tid & 63;
  const int hb = (tid >> 6) & 31;
  const int kb = tid >> 11;
  const int h = hb * 16 + (lane & 15);
  const int k = kb * 32 + (lane >> 4) * 8;
  const float* src = W + (size_t)h * D_ + k;
  float4 a = *(const float4*)src;
  float4 c = *(const float4*)(src + 4);
  s16x8 o;
  o[0] = (short)f2bf(a.x); o[1] = (short)f2bf(a.y);
  o[2] = (short)f2bf(a.z); o[3] = (short)f2bf(a.w);
  o[4] = (short)f2bf(c.x); o[5] = (short)f2bf(c.y);
  o[6] = (short)f2bf(c.z); o[7] = (short)f2bf(c.w);
  *(s16x8*)(Wp + (size_t)tid * 8) = o;
}

// ---------------- inp' = x @ W_in^T + b_in + b_ctx ----------------
__global__ void k_inp(const float* __restrict__ x, const float* __restrict__ W_in,
                      const float* __restrict__ b_in, const float* __restrict__ b_ctx,
                      float* __restrict__ inp_pb) {
  const int b = blockIdx.x, t = threadIdx.x;
  __shared__ float xs[D_];
  xs[t] = x[b * D_ + t];
  xs[t + 256] = x[b * D_ + t + 256];
  __syncthreads();
  for (int h = t; h < H_; h += 256) {
    const float4* wr = (const float4*)(W_in + (size_t)h * D_);
    float acc = 0.f;
#pragma unroll 4
    for (int d4 = 0; d4 < 128; ++d4) {
      float4 w = wr[d4];
      acc += w.x * xs[d4 * 4] + w.y * xs[d4 * 4 + 1] + w.z * xs[d4 * 4 + 2] +
             w.w * xs[d4 * 4 + 3];
    }
    inp_pb[b * H_ + h] = acc + b_in[h] + b_ctx[h];
  }
}

// ---------------- att[b,s] = sum_h V[h]*tanh(inp'[b,h] + (W_ctx@ctx^T)[h,s]) ----
// 512 thr / 8 waves; wave = 64h x 64s (acc[4][4]). Round-7 skeleton, but A
// fragments come from the PACKED Wp layout: each of the 8 per-iter A-loads is
// a contiguous 1KB burst (base + lane*16) instead of 64 scattered 16B reads
// at stride 1024. B: nt f32 loads -> reg cvt -> dbuf LDS, 16B XOR swizzle.
__global__ __launch_bounds__(512, 2) void k_att(
    const float* __restrict__ context, const unsigned short* __restrict__ Wp,
    const float* __restrict__ inp_pb, const float* __restrict__ V,
    float* __restrict__ att) {
  __shared__ char bt[2][8192];  // [s 64][k 64] bf16, 128B rows, swizzled
  __shared__ float red[8][64];
  const int tid = threadIdx.x;
  const int wave = tid >> 6, lane = tid & 63;
  const int b = blockIdx.y, s0 = blockIdx.x * 64;
  const float* ctxb = context + ((size_t)b * S_ + s0) * D_;
  const int hbase = wave * 64;
  const int bln = lane & 15, blh = lane >> 4;

  // staging: thread -> row srow = tid>>3 (0..63), k-chunk (tid&7)*8
  const int srow = tid >> 3, kc8 = (tid & 7) * 8;
  const int sbyte = srow * 128 + ((kc8 * 2) ^ ((srow & 7) << 4));
  const float* gsrc = ctxb + (size_t)srow * D_ + kc8;

  // packed A base for this wave: frag (kb = 2t+kk, hb = wave*4+m) at
  // ((kb*32 + hb)*64 + lane)*8 shorts
  const unsigned short* ap = Wp + ((size_t)(wave * 4) * 64 + lane) * 8;

  f32x4 acc[4][4];
#pragma unroll
  for (int m = 0; m < 4; ++m)
#pragma unroll
    for (int n = 0; n < 4; ++n) acc[m][n] = f32x4{0.f, 0.f, 0.f, 0.f};

  f32x4 stg0, stg1;
  auto load_nt = [&](int t) {
    stg0 = __builtin_nontemporal_load((const f32x4*)(gsrc + t * 64));
    stg1 = __builtin_nontemporal_load((const f32x4*)(gsrc + t * 64 + 4));
  };
  auto cvt_write = [&](int buf) {
    s16x8 hb;
    hb[0] = (short)f2bf(stg0[0]); hb[1] = (short)f2bf(stg0[1]);
    hb[2] = (short)f2bf(stg0[2]); hb[3] = (short)f2bf(stg0[3]);
    hb[4] = (short)f2bf(stg1[0]); hb[5] = (short)f2bf(stg1[1]);
    hb[6] = (short)f2bf(stg1[2]); hb[7] = (short)f2bf(stg1[3]);
    *(s16x8*)(&bt[buf][sbyte]) = hb;
  };

  load_nt(0);
  cvt_write(0);
  __syncthreads();

  for (int t = 0; t < 8; ++t) {
    if (t < 7) load_nt(t + 1);  // issue early; consumed after MFMAs (T14)
    const char* cur = bt[t & 1];
#pragma unroll
    for (int kk = 0; kk < 2; ++kk) {
      const unsigned short* ak = ap + (size_t)(t * 2 + kk) * 32 * 512;
      s16x8 bfrag[4], af[4];
#pragma unroll
      for (int n = 0; n < 4; ++n) {
        const int sr = n * 16 + bln;
        const int off = (kk * 64 + blh * 16) ^ ((sr & 7) << 4);
        bfrag[n] = *(const s16x8*)(cur + sr * 128 + off);
      }
#pragma unroll
      for (int m = 0; m < 4; ++m)
        af[m] = *(const s16x8*)(ak + (size_t)m * 512);  // contiguous 1KB burst
#pragma unroll
      for (int m = 0; m < 4; ++m)
#pragma unroll
        for (int n = 0; n < 4; ++n)
          acc[m][n] = __builtin_amdgcn_mfma_f32_16x16x32_bf16(af[m], bfrag[n],
                                                              acc[m][n], 0, 0, 0);
    }
    if (t < 7) cvt_write((t + 1) & 1);  // other buffer; readers synced at t-1
    __syncthreads();
  }

  // epilogue: tanh + V-dot, reduce over h
  float attp[4] = {0.f, 0.f, 0.f, 0.f};
  const float* ib = inp_pb + b * H_;
#pragma unroll
  for (int m = 0; m < 4; ++m) {
#pragma unroll
    for (int j = 0; j < 4; ++j) {
      int h = hbase + m * 16 + (blh << 2) + j;
      float c = ib[h];
      float vh = V[h];
#pragma unroll
      for (int n = 0; n < 4; ++n) {
        float x = acc[m][n][j] + c;
        x = fminf(fmaxf(x, -15.f), 15.f);
        float e = __expf(2.f * x);
        attp[n] += vh * __fdividef(e - 1.f, e + 1.f);
      }
    }
  }
#pragma unroll
  for (int n = 0; n < 4; ++n) {
    attp[n] += __shfl_xor(attp[n], 16, 64);
    attp[n] += __shfl_xor(attp[n], 32, 64);
  }
  if (lane < 16) {
#pragma unroll
    for (int n = 0; n < 4; ++n) red[wave][n * 16 + lane] = attp[n];
  }
  __syncthreads();
  if (tid < 64) {
    float s = 0.f;
#pragma unroll
    for (int w = 0; w < 8; ++w) s += red[w][tid];
    att[(size_t)b * S_ + s0 + tid] = s;
  }
}

// ---------------- masked softmax over S -> alpha ----------------
__global__ void k_softmax(const float* __restrict__ att, const void* __restrict__ mask,
                          const int* __restrict__ flag, float* __restrict__ alpha) {
  const int b = blockIdx.x, t = threadIdx.x;
  const int c = *flag;
  const int mtype = (c & 2) ? 2 : (c & 1);  // 2=float, 1=bytes, 0=int32
  __shared__ float sm[4];
  const unsigned char* m8 = (const unsigned char*)mask;
  const int* m32 = (const int*)mask;
  const float* mf = (const float*)mask;
  float vals[8];
  float mx = -3.0e38f;
#pragma unroll
  for (int i = 0; i < 8; ++i) {
    int s = t + i * 256;
    size_t idx = (size_t)b * S_ + s;
    int msk = (mtype == 1) ? (int)m8[idx] : (mtype == 2) ? (mf[idx] != 0.f) : m32[idx];
    float v = msk ? -__builtin_inff() : att[idx];
    vals[i] = v;
    mx = fmaxf(mx, v);
  }
  for (int off = 32; off; off >>= 1) mx = fmaxf(mx, __shfl_xor(mx, off, 64));
  if ((t & 63) == 0) sm[t >> 6] = mx;
  __syncthreads();
  mx = fmaxf(fmaxf(sm[0], sm[1]), fmaxf(sm[2], sm[3]));
  float es[8];
  float sum = 0.f;
#pragma unroll
  for (int i = 0; i < 8; ++i) {
    es[i] = __expf(vals[i] - mx);
    sum += es[i];
  }
  for (int off = 32; off; off >>= 1) sum += __shfl_xor(sum, off, 64);
  __syncthreads();
  if ((t & 63) == 0) sm[t >> 6] = sum;
  __syncthreads();
  sum = sm[0] + sm[1] + sm[2] + sm[3];
  float inv = __fdividef(1.f, sum);
#pragma unroll
  for (int i = 0; i < 8; ++i) alpha[(size_t)b * S_ + t + i * 256] = es[i] * inv;
}

// ---------------- y partials: y[b,d] = sum_s alpha*context (f32) ----------------
__global__ void k_ypart(const float* __restrict__ context,
                        const float* __restrict__ alpha, float* __restrict__ y_part) {
  const int chunk = blockIdx.x, b = blockIdx.y, t = threadIdx.x;
  __shared__ float al[256];
  __shared__ float4 part[128];
  al[t] = alpha[(size_t)b * S_ + chunk * 256 + t];
  __syncthreads();
  const int d4 = t & 127, sr = t >> 7;
  const float4* base = (const float4*)(context + ((size_t)b * S_ + chunk * 256) * D_);
  float4 acc = make_float4(0.f, 0.f, 0.f, 0.f);
  for (int i = 0; i < 128; ++i) {
    int s = sr + 2 * i;
    float4 v = base[(size_t)s * 128 + d4];
    float a = al[s];
    acc.x += a * v.x; acc.y += a * v.y; acc.z += a * v.z; acc.w += a * v.w;
  }
  if (sr == 1) part[d4] = acc;
  __syncthreads();
  if (sr == 0) {
    float4 o = part[d4];
    o.x += acc.x; o.y += acc.y; o.z += acc.z; o.w += acc.w;
    *(float4*)(y_part + ((size_t)(b * 8 + chunk)) * D_ + d4 * 4) = o;
  }
}

// ---------------- hidden = W_ctx @ y + b_ctx (exact f32) ----------------
__global__ void k_hidden(const float* __restrict__ y_part, const float* __restrict__ W_ctx,
                         const float* __restrict__ b_ctx, float* __restrict__ hidden) {
  const int b = blockIdx.x, t = threadIdx.x;
  __shared__ float ys[D_];
  for (int d = t; d < D_; d += 256) {
    float s = 0.f;
#pragma unroll
    for (int c = 0; c < 8; ++c) s += y_part[((size_t)(b * 8 + c)) * D_ + d];
    ys[d] = s;
  }
  __syncthreads();
  for (int h = t; h < H_; h += 256) {
    const float4* wr = (const float4*)(W_ctx + (size_t)h * D_);
    float acc = 0.f;
#pragma unroll 4
    for (int d4 = 0; d4 < 128; ++d4) {
      float4 w = wr[d4];
      acc += w.x * ys[d4 * 4] + w.y * ys[d4 * 4 + 1] + w.z * ys[d4 * 4 + 2] +
             w.w * ys[d4 * 4 + 3];
    }
    hidden[b * H_ + h] = acc + b_ctx[h];
  }
}

extern "C" void kernel_launch(void* const* d_in, const int* in_sizes, int n_in,
                              void* d_out, int out_size, void* d_ws, size_t ws_size,
                              hipStream_t stream) {
  (void)in_sizes; (void)n_in; (void)out_size; (void)ws_size;
  const float* x = (const float*)d_in[0];
  const float* context = (const float*)d_in[1];
  const void* mask = d_in[2];
  const float* W_in = (const float*)d_in[3];
  const float* b_in = (const float*)d_in[4];
  const float* W_ctx = (const float*)d_in[5];
  const float* b_ctx = (const float*)d_in[6];
  const float* V = (const float*)d_in[7];

  float* out_hidden = (float*)d_out;           // [B,H]
  float* out_alpha = (float*)d_out + B_ * H_;  // [B,S]

  // workspace: inp_pb 128K | att 512K | y_part 1M | flag | Wp 512K
  char* ws = (char*)d_ws;
  float* inp_pb = (float*)ws;                            // B*H f32
  float* att = (float*)(ws + 131072);                    // B*S f32
  float* y_part = (float*)(ws + 655360);                 // B*8*D f32
  int* flag = (int*)(ws + 1703936);                      // 16 ints
  unsigned short* Wp = (unsigned short*)(ws + 1704000);  // H*D bf16 packed

  k_zero<<<1, 64, 0, stream>>>(flag);
  k_detect<<<128, 256, 0, stream>>>((const unsigned int*)mask, flag);
  k_pack<<<128, 256, 0, stream>>>(W_ctx, Wp);
  k_inp<<<B_, 256, 0, stream>>>(x, W_in, b_in, b_ctx, inp_pb);
  k_att<<<dim3(S_ / 64, B_), 512, 0, stream>>>(context, Wp, inp_pb, V, att);
  k_softmax<<<B_, 256, 0, stream>>>(att, mask, flag, out_alpha);
  k_ypart<<<dim3(8, B_), 256, 0, stream>>>(context, out_alpha, y_part);
  k_hidden<<<B_, 256, 0, stream>>>(y_part, W_ctx, b_ctx, out_hidden);
}

// Round 9
// 233.858 us; speedup vs baseline: 1.8442x; 1.0543x over previous
//
#include <hip/hip_runtime.h>
#include <hip/hip_bf16.h>
#include <cstdint>

#define B_ 64
#define S_ 2048
#define D_ 512
#define H_ 512

typedef short s16x8 __attribute__((ext_vector_type(8)));
typedef float f32x4 __attribute__((ext_vector_type(4)));

static __device__ __forceinline__ unsigned short f2bf(float f) {
  __bf16 h = (__bf16)f;
  return __builtin_bit_cast(unsigned short, h);
}

// ---------------- mask dtype detection (parallel) ----------------
__global__ void k_zero(int* __restrict__ flag) {
  if (threadIdx.x == 0) *flag = 0;
}
__global__ void k_detect(const unsigned int* __restrict__ mw, int* __restrict__ flag) {
  int i = blockIdx.x * 256 + threadIdx.x;  // 128 blocks x 256 = 32768
  unsigned w = mw[i];
  int bits = 0;
  if (w == 0x3F800000u) bits = 2;
  else if (w > 1u) bits = 1;
  unsigned long long a1 = __ballot(bits & 1);
  unsigned long long a2 = __ballot(bits & 2);
  if ((threadIdx.x & 63) == 0) {
    int v = (a1 ? 1 : 0) | (a2 ? 2 : 0);
    if (v) atomicOr(flag, v);
  }
}

// ---------------- pack W_ctx into MFMA-fragment-major bf16 layout ----------------
// Wp[((kb*32 + hb)*64 + lane)*8 + e] = bf16(W_ctx[hb*16 + (lane&15)]
//                                               [kb*32 + (lane>>4)*8 + e])
__global__ __launch_bounds__(256) void k_pack(const float* __restrict__ W,
                                              unsigned short* __restrict__ Wp) {
  const int tid = blockIdx.x * 256 + threadIdx.x;  // 128 blocks -> 32768 threads
  const int lane = tid & 63;
  const int hb = (tid >> 6) & 31;
  const int kb = tid >> 11;
  const int h = hb * 16 + (lane & 15);
  const int k = kb * 32 + (lane >> 4) * 8;
  const float* src = W + (size_t)h * D_ + k;
  float4 a = *(const float4*)src;
  float4 c = *(const float4*)(src + 4);
  s16x8 o;
  o[0] = (short)f2bf(a.x); o[1] = (short)f2bf(a.y);
  o[2] = (short)f2bf(a.z); o[3] = (short)f2bf(a.w);
  o[4] = (short)f2bf(c.x); o[5] = (short)f2bf(c.y);
  o[6] = (short)f2bf(c.z); o[7] = (short)f2bf(c.w);
  *(s16x8*)(Wp + (size_t)tid * 8) = o;
}

// ---------------- inp' = x @ W_in^T + b_in + b_ctx ----------------
__global__ void k_inp(const float* __restrict__ x, const float* __restrict__ W_in,
                      const float* __restrict__ b_in, const float* __restrict__ b_ctx,
                      float* __restrict__ inp_pb) {
  const int b = blockIdx.x, t = threadIdx.x;
  __shared__ float xs[D_];
  xs[t] = x[b * D_ + t];
  xs[t + 256] = x[b * D_ + t + 256];
  __syncthreads();
  for (int h = t; h < H_; h += 256) {
    const float4* wr = (const float4*)(W_in + (size_t)h * D_);
    float acc = 0.f;
#pragma unroll 4
    for (int d4 = 0; d4 < 128; ++d4) {
      float4 w = wr[d4];
      acc += w.x * xs[d4 * 4] + w.y * xs[d4 * 4 + 1] + w.z * xs[d4 * 4 + 2] +
             w.w * xs[d4 * 4 + 3];
    }
    inp_pb[b * H_ + h] = acc + b_in[h] + b_ctx[h];
  }
}

// ---------------- att[b,s] = sum_h V[h]*tanh(inp'[b,h] + (W_ctx@ctx^T)[h,s]) ----
// Round-8 skeleton + (1) depth-2 staging: two reg sets by tile parity
// (sA = even tiles -> bt[0], sB = odd -> bt[1]); tile t+2 issued at iter t,
// written end of iter t+1 (~1.7 iters HBM cover). (2) loop barrier is
// lgkmcnt(0)+s_barrier (NO vmcnt drain) so in-flight stg loads survive.
// A-loads issue first, sched_barrier pins them ahead of the stg issue so the
// MFMA wait is vmcnt(2), never 0.
__global__ __launch_bounds__(512, 2) void k_att(
    const float* __restrict__ context, const unsigned short* __restrict__ Wp,
    const float* __restrict__ inp_pb, const float* __restrict__ V,
    float* __restrict__ att) {
  __shared__ char bt[2][8192];  // [s 64][k 64] bf16, 128B rows, swizzled
  __shared__ float red[8][64];
  const int tid = threadIdx.x;
  const int wave = tid >> 6, lane = tid & 63;
  const int b = blockIdx.y, s0 = blockIdx.x * 64;
  const float* ctxb = context + ((size_t)b * S_ + s0) * D_;
  const int hbase = wave * 64;
  const int bln = lane & 15, blh = lane >> 4;

  // staging: thread -> row srow = tid>>3 (0..63), k-chunk (tid&7)*8
  const int srow = tid >> 3, kc8 = (tid & 7) * 8;
  const int sbyte = srow * 128 + ((kc8 * 2) ^ ((srow & 7) << 4));
  const float* gsrc = ctxb + (size_t)srow * D_ + kc8;

  // packed A base: frag (kb = 2t+kk, hb = wave*4+m) at ((kb*32+hb)*64+lane)*8
  const unsigned short* ap = Wp + ((size_t)(wave * 4) * 64 + lane) * 8;

  f32x4 acc[4][4];
#pragma unroll
  for (int m = 0; m < 4; ++m)
#pragma unroll
    for (int n = 0; n < 4; ++n) acc[m][n] = f32x4{0.f, 0.f, 0.f, 0.f};

  f32x4 sA0, sA1, sB0, sB1;  // depth-2 staging sets (even / odd tiles)
  auto load_A = [&](int t) {
    sA0 = __builtin_nontemporal_load((const f32x4*)(gsrc + t * 64));
    sA1 = __builtin_nontemporal_load((const f32x4*)(gsrc + t * 64 + 4));
  };
  auto load_B = [&](int t) {
    sB0 = __builtin_nontemporal_load((const f32x4*)(gsrc + t * 64));
    sB1 = __builtin_nontemporal_load((const f32x4*)(gsrc + t * 64 + 4));
  };
  auto cvt_A = [&]() {  // even tile -> bt[0]
    s16x8 hb;
    hb[0] = (short)f2bf(sA0[0]); hb[1] = (short)f2bf(sA0[1]);
    hb[2] = (short)f2bf(sA0[2]); hb[3] = (short)f2bf(sA0[3]);
    hb[4] = (short)f2bf(sA1[0]); hb[5] = (short)f2bf(sA1[1]);
    hb[6] = (short)f2bf(sA1[2]); hb[7] = (short)f2bf(sA1[3]);
    *(s16x8*)(&bt[0][sbyte]) = hb;
  };
  auto cvt_B = [&]() {  // odd tile -> bt[1]
    s16x8 hb;
    hb[0] = (short)f2bf(sB0[0]); hb[1] = (short)f2bf(sB0[1]);
    hb[2] = (short)f2bf(sB0[2]); hb[3] = (short)f2bf(sB0[3]);
    hb[4] = (short)f2bf(sB1[0]); hb[5] = (short)f2bf(sB1[1]);
    hb[6] = (short)f2bf(sB1[2]); hb[7] = (short)f2bf(sB1[3]);
    *(s16x8*)(&bt[1][sbyte]) = hb;
  };

  // prologue: tiles 0,1 loaded; tile 0 written
  load_A(0);
  load_B(1);
  cvt_A();  // compiler waits only for sA (sB stays in flight)
  asm volatile("s_waitcnt lgkmcnt(0)" ::: "memory");
  __builtin_amdgcn_s_barrier();
  __builtin_amdgcn_sched_barrier(0);

#pragma unroll
  for (int t = 0; t < 8; ++t) {
    const char* cur = bt[t & 1];
    // (1) A-frag loads for both kk halves (8 contiguous 1KB bursts, L2)
    s16x8 af[2][4];
#pragma unroll
    for (int kk = 0; kk < 2; ++kk)
#pragma unroll
      for (int m = 0; m < 4; ++m)
        af[kk][m] = *(const s16x8*)(ap + (size_t)(t * 2 + kk) * 32 * 512 +
                                    (size_t)m * 512);
    __builtin_amdgcn_sched_barrier(0);  // pin A-loads before stg issue
    // (2) stage-load tile t+2; stays in flight across the barrier
    if (t < 6) {
      if ((t & 1) == 0) load_A(t + 2); else load_B(t + 2);
    }
    // (3) MFMA phases on bt[t&1]
#pragma unroll
    for (int kk = 0; kk < 2; ++kk) {
      s16x8 bfrag[4];
#pragma unroll
      for (int n = 0; n < 4; ++n) {
        const int sr = n * 16 + bln;
        const int off = (kk * 64 + blh * 16) ^ ((sr & 7) << 4);
        bfrag[n] = *(const s16x8*)(cur + sr * 128 + off);
      }
#pragma unroll
      for (int m = 0; m < 4; ++m)
#pragma unroll
        for (int n = 0; n < 4; ++n)
          acc[m][n] = __builtin_amdgcn_mfma_f32_16x16x32_bf16(af[kk][m], bfrag[n],
                                                              acc[m][n], 0, 0, 0);
    }
    // (4) write tile t+1 (loaded at iter t-1: ~1.7 iters of cover)
    if (t < 7) {
      if (((t + 1) & 1) == 0) cvt_A(); else cvt_B();
    }
    // (5) barrier WITHOUT vmcnt drain
    asm volatile("s_waitcnt lgkmcnt(0)" ::: "memory");
    __builtin_amdgcn_s_barrier();
    __builtin_amdgcn_sched_barrier(0);
  }

  // epilogue: tanh + V-dot, reduce over h
  float attp[4] = {0.f, 0.f, 0.f, 0.f};
  const float* ib = inp_pb + b * H_;
#pragma unroll
  for (int m = 0; m < 4; ++m) {
#pragma unroll
    for (int j = 0; j < 4; ++j) {
      int h = hbase + m * 16 + (blh << 2) + j;
      float c = ib[h];
      float vh = V[h];
#pragma unroll
      for (int n = 0; n < 4; ++n) {
        float x = acc[m][n][j] + c;
        x = fminf(fmaxf(x, -15.f), 15.f);
        float e = __expf(2.f * x);
        attp[n] += vh * __fdividef(e - 1.f, e + 1.f);
      }
    }
  }
#pragma unroll
  for (int n = 0; n < 4; ++n) {
    attp[n] += __shfl_xor(attp[n], 16, 64);
    attp[n] += __shfl_xor(attp[n], 32, 64);
  }
  if (lane < 16) {
#pragma unroll
    for (int n = 0; n < 4; ++n) red[wave][n * 16 + lane] = attp[n];
  }
  __syncthreads();
  if (tid < 64) {
    float s = 0.f;
#pragma unroll
    for (int w = 0; w < 8; ++w) s += red[w][tid];
    att[(size_t)b * S_ + s0 + tid] = s;
  }
}

// ---------------- masked softmax over S -> alpha ----------------
__global__ void k_softmax(const float* __restrict__ att, const void* __restrict__ mask,
                          const int* __restrict__ flag, float* __restrict__ alpha) {
  const int b = blockIdx.x, t = threadIdx.x;
  const int c = *flag;
  const int mtype = (c & 2) ? 2 : (c & 1);  // 2=float, 1=bytes, 0=int32
  __shared__ float sm[4];
  const unsigned char* m8 = (const unsigned char*)mask;
  const int* m32 = (const int*)mask;
  const float* mf = (const float*)mask;
  float vals[8];
  float mx = -3.0e38f;
#pragma unroll
  for (int i = 0; i < 8; ++i) {
    int s = t + i * 256;
    size_t idx = (size_t)b * S_ + s;
    int msk = (mtype == 1) ? (int)m8[idx] : (mtype == 2) ? (mf[idx] != 0.f) : m32[idx];
    float v = msk ? -__builtin_inff() : att[idx];
    vals[i] = v;
    mx = fmaxf(mx, v);
  }
  for (int off = 32; off; off >>= 1) mx = fmaxf(mx, __shfl_xor(mx, off, 64));
  if ((t & 63) == 0) sm[t >> 6] = mx;
  __syncthreads();
  mx = fmaxf(fmaxf(sm[0], sm[1]), fmaxf(sm[2], sm[3]));
  float es[8];
  float sum = 0.f;
#pragma unroll
  for (int i = 0; i < 8; ++i) {
    es[i] = __expf(vals[i] - mx);
    sum += es[i];
  }
  for (int off = 32; off; off >>= 1) sum += __shfl_xor(sum, off, 64);
  __syncthreads();
  if ((t & 63) == 0) sm[t >> 6] = sum;
  __syncthreads();
  sum = sm[0] + sm[1] + sm[2] + sm[3];
  float inv = __fdividef(1.f, sum);
#pragma unroll
  for (int i = 0; i < 8; ++i) alpha[(size_t)b * S_ + t + i * 256] = es[i] * inv;
}

// ---------------- y partials: y[b,d] = sum_s alpha*context (f32) ----------------
__global__ void k_ypart(const float* __restrict__ context,
                        const float* __restrict__ alpha, float* __restrict__ y_part) {
  const int chunk = blockIdx.x, b = blockIdx.y, t = threadIdx.x;
  __shared__ float al[256];
  __shared__ float4 part[128];
  al[t] = alpha[(size_t)b * S_ + chunk * 256 + t];
  __syncthreads();
  const int d4 = t & 127, sr = t >> 7;
  const float4* base = (const float4*)(context + ((size_t)b * S_ + chunk * 256) * D_);
  float4 acc = make_float4(0.f, 0.f, 0.f, 0.f);
  for (int i = 0; i < 128; ++i) {
    int s = sr + 2 * i;
    float4 v = base[(size_t)s * 128 + d4];
    float a = al[s];
    acc.x += a * v.x; acc.y += a * v.y; acc.z += a * v.z; acc.w += a * v.w;
  }
  if (sr == 1) part[d4] = acc;
  __syncthreads();
  if (sr == 0) {
    float4 o = part[d4];
    o.x += acc.x; o.y += acc.y; o.z += acc.z; o.w += acc.w;
    *(float4*)(y_part + ((size_t)(b * 8 + chunk)) * D_ + d4 * 4) = o;
  }
}

// ---------------- hidden = W_ctx @ y + b_ctx (exact f32) ----------------
__global__ void k_hidden(const float* __restrict__ y_part, const float* __restrict__ W_ctx,
                         const float* __restrict__ b_ctx, float* __restrict__ hidden) {
  const int b = blockIdx.x, t = threadIdx.x;
  __shared__ float ys[D_];
  for (int d = t; d < D_; d += 256) {
    float s = 0.f;
#pragma unroll
    for (int c = 0; c < 8; ++c) s += y_part[((size_t)(b * 8 + c)) * D_ + d];
    ys[d] = s;
  }
  __syncthreads();
  for (int h = t; h < H_; h += 256) {
    const float4* wr = (const float4*)(W_ctx + (size_t)h * D_);
    float acc = 0.f;
#pragma unroll 4
    for (int d4 = 0; d4 < 128; ++d4) {
      float4 w = wr[d4];
      acc += w.x * ys[d4 * 4] + w.y * ys[d4 * 4 + 1] + w.z * ys[d4 * 4 + 2] +
             w.w * ys[d4 * 4 + 3];
    }
    hidden[b * H_ + h] = acc + b_ctx[h];
  }
}

extern "C" void kernel_launch(void* const* d_in, const int* in_sizes, int n_in,
                              void* d_out, int out_size, void* d_ws, size_t ws_size,
                              hipStream_t stream) {
  (void)in_sizes; (void)n_in; (void)out_size; (void)ws_size;
  const float* x = (const float*)d_in[0];
  const float* context = (const float*)d_in[1];
  const void* mask = d_in[2];
  const float* W_in = (const float*)d_in[3];
  const float* b_in = (const float*)d_in[4];
  const float* W_ctx = (const float*)d_in[5];
  const float* b_ctx = (const float*)d_in[6];
  const float* V = (const float*)d_in[7];

  float* out_hidden = (float*)d_out;           // [B,H]
  float* out_alpha = (float*)d_out + B_ * H_;  // [B,S]

  // workspace: inp_pb 128K | att 512K | y_part 1M | flag | Wp 512K
  char* ws = (char*)d_ws;
  float* inp_pb = (float*)ws;                            // B*H f32
  float* att = (float*)(ws + 131072);                    // B*S f32
  float* y_part = (float*)(ws + 655360);                 // B*8*D f32
  int* flag = (int*)(ws + 1703936);                      // 16 ints
  unsigned short* Wp = (unsigned short*)(ws + 1704000);  // H*D bf16 packed

  k_zero<<<1, 64, 0, stream>>>(flag);
  k_detect<<<128, 256, 0, stream>>>((const unsigned int*)mask, flag);
  k_pack<<<128, 256, 0, stream>>>(W_ctx, Wp);
  k_inp<<<B_, 256, 0, stream>>>(x, W_in, b_in, b_ctx, inp_pb);
  k_att<<<dim3(S_ / 64, B_), 512, 0, stream>>>(context, Wp, inp_pb, V, att);
  k_softmax<<<B_, 256, 0, stream>>>(att, mask, flag, out_alpha);
  k_ypart<<<dim3(8, B_), 256, 0, stream>>>(context, out_alpha, y_part);
  k_hidden<<<B_, 256, 0, stream>>>(y_part, W_ctx, b_ctx, out_hidden);
}